// Round 1
// baseline (382.743 us; speedup 1.0000x reference)
//
#include <hip/hip_runtime.h>
#include <cstddef>
#include <cstdint>

typedef __attribute__((ext_vector_type(8))) short bf16x8;   // 8 bf16 = 4 VGPR
typedef __attribute__((ext_vector_type(4))) short short4v;  // 4 bf16 = 8B
typedef __attribute__((ext_vector_type(16))) float f32x16;  // MFMA 32x32 acc

static constexpr int TM = 128;   // edges per block
static constexpr float LN2 = 0.69314718055994530942f;

__device__ __forceinline__ unsigned short f2bf(float f) {
  unsigned int u = __float_as_uint(f);
  u += 0x7fffu + ((u >> 16) & 1u);   // RNE
  return (unsigned short)(u >> 16);
}

__device__ __forceinline__ float shifted_softplus(float x) {
  // softplus(x) - ln2, numerically stable
  return fmaxf(x, 0.0f) + log1pf(__expf(-fabsf(x))) - LN2;
}

// ---- prep: h (N*64 f32) -> bf16 ----
__global__ void prep_h_kernel(const float* __restrict__ h,
                              unsigned short* __restrict__ hbf, int n4) {
  int i = blockIdx.x * 256 + threadIdx.x;
  if (i < n4) {
    float4 v = reinterpret_cast<const float4*>(h)[i];
    short4v o;
    o.x = (short)f2bf(v.x); o.y = (short)f2bf(v.y);
    o.z = (short)f2bf(v.z); o.w = (short)f2bf(v.w);
    reinterpret_cast<short4v*>(hbf)[i] = o;
  }
}

// ---- prep: pack W1^T, W2^T into MFMA-fragment order (bf16) ----
// Wp1[((mt*12+kk)*64 + l)*8 + i] = W1[kk*16 + (l>>5)*8 + i][mt*32 + (l&31)]
// Wp2[((mt*8 +kk)*64 + l)*8 + i] = W2[kk*16 + (l>>5)*8 + i][mt*32 + (l&31)]
__global__ void prep_w_kernel(const float* __restrict__ W1,
                              const float* __restrict__ W2,
                              unsigned short* __restrict__ Wp1,
                              unsigned short* __restrict__ Wp2) {
  int j = blockIdx.x * 256 + threadIdx.x;
  if (j < 4 * 12 * 64) {
    int mt = j / (12 * 64);
    int kk = (j / 64) % 12;
    int l  = j % 64;
    int f  = mt * 32 + (l & 31);
    int kb = kk * 16 + (l >> 5) * 8;
    #pragma unroll
    for (int i = 0; i < 8; ++i)
      Wp1[(size_t)j * 8 + i] = f2bf(W1[(size_t)(kb + i) * 128 + f]);
  } else if (j < 4 * 12 * 64 + 2 * 8 * 64) {
    int jj = j - 4 * 12 * 64;
    int mt = jj / (8 * 64);
    int kk = (jj / 64) % 8;
    int l  = jj % 64;
    int oc = mt * 32 + (l & 31);
    int kb = kk * 16 + (l >> 5) * 8;
    #pragma unroll
    for (int i = 0; i < 8; ++i)
      Wp2[(size_t)jj * 8 + i] = f2bf(W2[(size_t)(kb + i) * 64 + oc]);
  }
}

// ---- main fused kernel ----
// Per block: 128 edges. Stage concat tile (128 x 192 bf16) in LDS.
// GEMM1 (swapped): x^T = W1^T(128x192) @ concat^T(192x128)  via 32x32x16 MFMA
// softplus -> bf16 -> Xtile (wave-private rows, no barrier)
// GEMM2 (swapped): out^T = W2^T(64x128) @ x(128 rows x128 f)
__global__ __launch_bounds__(256, 2)
void edge_mlp_kernel(const float* __restrict__ ea,
                     const int* __restrict__ eidx,
                     const float* __restrict__ b1,
                     const float* __restrict__ b2,
                     const unsigned short* __restrict__ hbf,
                     const unsigned short* __restrict__ Wp1,
                     const unsigned short* __restrict__ Wp2,
                     float* __restrict__ out,
                     int E) {
  __shared__ __align__(16) unsigned char Atile[TM * 384]; // 128 rows x 192 bf16, 24 chunks/row
  __shared__ __align__(16) unsigned char Xtile[TM * 256]; // 128 rows x 128 bf16, 16 chunks/row

  const int tid   = threadIdx.x;
  const int ebase = blockIdx.x * TM;

  // ---- stage h[src] (chunks 0..7), h[dst] (chunks 8..15), 16B each, XOR swizzle ----
  #pragma unroll
  for (int it = 0; it < 8; ++it) {
    int ci    = it * 256 + tid;       // 0..2047 = 128 rows * 16 chunks
    int row   = ci >> 4;
    int which = (ci >> 3) & 1;
    int c     = ci & 7;
    int node  = eidx[(size_t)which * E + (ebase + row)];
    bf16x8 v = *reinterpret_cast<const bf16x8*>(hbf + (size_t)node * 64 + c * 8);
    int chunk = (which * 8 + c) ^ (row & 7);
    *reinterpret_cast<bf16x8*>(Atile + row * 384 + chunk * 16) = v;
  }
  // ---- stage edge_attr f32 -> bf16 (chunks 16..23) ----
  #pragma unroll
  for (int it = 0; it < 8; ++it) {
    int ci  = it * 256 + tid;         // 0..2047 = 128 rows * 16 quads
    int row = ci >> 4;
    int qc  = ci & 15;
    float4 v = *reinterpret_cast<const float4*>(ea + (size_t)(ebase + row) * 64 + qc * 4);
    short4v o;
    o.x = (short)f2bf(v.x); o.y = (short)f2bf(v.y);
    o.z = (short)f2bf(v.z); o.w = (short)f2bf(v.w);
    int chunk = (16 + (qc >> 1)) ^ (row & 7);
    *reinterpret_cast<short4v*>(Atile + row * 384 + chunk * 16 + (qc & 1) * 8) = o;
  }
  __syncthreads();

  const int lane = tid & 63;
  const int w    = tid >> 6;
  const int lo   = lane & 31;
  const int hi   = lane >> 5;
  const int erow = w * 32 + lo;       // this wave owns rows [w*32, w*32+32)
  const int rsw  = erow & 7;

  // ---- GEMM1: x^T = W1^T @ concat^T, M=128 feats (4 m-tiles), N=32 edges ----
  f32x16 acc[4];
  #pragma unroll
  for (int m = 0; m < 4; ++m) acc[m] = (f32x16)0.0f;

  #pragma unroll
  for (int kk = 0; kk < 12; ++kk) {
    bf16x8 bfr = *reinterpret_cast<const bf16x8*>(
        Atile + erow * 384 + (((kk * 2 + hi) ^ rsw) * 16));
    #pragma unroll
    for (int mt = 0; mt < 4; ++mt) {
      bf16x8 afr = *reinterpret_cast<const bf16x8*>(
          Wp1 + ((size_t)(mt * 12 + kk) * 64 + lane) * 8);
      acc[mt] = __builtin_amdgcn_mfma_f32_32x32x16_bf16(afr, bfr, acc[mt], 0, 0, 0);
    }
  }

  // ---- bias + shifted softplus -> bf16 -> Xtile (wave-private rows) ----
  #pragma unroll
  for (int mt = 0; mt < 4; ++mt) {
    #pragma unroll
    for (int g = 0; g < 4; ++g) {
      int f0 = mt * 32 + g * 8 + hi * 4;      // 4 consecutive features
      float4 bb = *reinterpret_cast<const float4*>(b1 + f0);
      short4v o;
      o.x = (short)f2bf(shifted_softplus(acc[mt][g * 4 + 0] + bb.x));
      o.y = (short)f2bf(shifted_softplus(acc[mt][g * 4 + 1] + bb.y));
      o.z = (short)f2bf(shifted_softplus(acc[mt][g * 4 + 2] + bb.z));
      o.w = (short)f2bf(shifted_softplus(acc[mt][g * 4 + 3] + bb.w));
      int chunk = (mt * 4 + g) ^ rsw;
      *reinterpret_cast<short4v*>(Xtile + erow * 256 + chunk * 16 + hi * 8) = o;
    }
  }
  // no barrier: each wave reads only its own 32 rows of Xtile

  // ---- GEMM2: out^T = W2^T @ x, M=64 ocs (2 m-tiles), K=128 ----
  f32x16 acc2[2];
  #pragma unroll
  for (int m = 0; m < 2; ++m) acc2[m] = (f32x16)0.0f;

  #pragma unroll
  for (int kk = 0; kk < 8; ++kk) {
    bf16x8 bfr = *reinterpret_cast<const bf16x8*>(
        Xtile + erow * 256 + (((kk * 2 + hi) ^ rsw) * 16));
    #pragma unroll
    for (int mt = 0; mt < 2; ++mt) {
      bf16x8 afr = *reinterpret_cast<const bf16x8*>(
          Wp2 + ((size_t)(mt * 8 + kk) * 64 + lane) * 8);
      acc2[mt] = __builtin_amdgcn_mfma_f32_32x32x16_bf16(afr, bfr, acc2[mt], 0, 0, 0);
    }
  }

  // ---- bias + store: out[e][oc], 16B per store ----
  #pragma unroll
  for (int mt = 0; mt < 2; ++mt) {
    #pragma unroll
    for (int g = 0; g < 4; ++g) {
      int oc0 = mt * 32 + g * 8 + hi * 4;     // 4 consecutive out features
      float4 bb = *reinterpret_cast<const float4*>(b2 + oc0);
      float4 o;
      o.x = acc2[mt][g * 4 + 0] + bb.x;
      o.y = acc2[mt][g * 4 + 1] + bb.y;
      o.z = acc2[mt][g * 4 + 2] + bb.z;
      o.w = acc2[mt][g * 4 + 3] + bb.w;
      *reinterpret_cast<float4*>(out + (size_t)(ebase + erow) * 64 + oc0) = o;
    }
  }
}

extern "C" void kernel_launch(void* const* d_in, const int* in_sizes, int n_in,
                              void* d_out, int out_size, void* d_ws, size_t ws_size,
                              hipStream_t stream) {
  const float* h  = (const float*)d_in[0];
  const float* ea = (const float*)d_in[1];
  const int*  idx = (const int*)d_in[2];
  const float* W1 = (const float*)d_in[3];
  const float* b1 = (const float*)d_in[4];
  const float* W2 = (const float*)d_in[5];
  const float* b2 = (const float*)d_in[6];
  float* out = (float*)d_out;

  const int N = in_sizes[0] / 64;      // 50000
  const int E = in_sizes[1] / 64;      // 800000

  // workspace layout
  unsigned short* hbf = (unsigned short*)d_ws;                       // N*64 bf16
  size_t off1 = (size_t)N * 64 * 2;                                  // 6,400,000 (16B aligned)
  unsigned short* Wp1 = (unsigned short*)((char*)d_ws + off1);       // 24576 bf16
  unsigned short* Wp2 = (unsigned short*)((char*)d_ws + off1 + 24576 * 2);

  int n4 = (N * 64) / 4;
  prep_h_kernel<<<(n4 + 255) / 256, 256, 0, stream>>>(h, hbf, n4);
  prep_w_kernel<<<16, 256, 0, stream>>>(W1, W2, Wp1, Wp2);

  int nblk = E / TM;                    // 6250
  edge_mlp_kernel<<<nblk, 256, 0, stream>>>(ea, idx, b1, b2, hbf, Wp1, Wp2, out, E);
}

// Round 3
// 170.702 us; speedup vs baseline: 2.2422x; 2.2422x over previous
//
#include <hip/hip_runtime.h>
#include <cstddef>
#include <cstdint>

typedef __attribute__((ext_vector_type(8))) short bf16x8;   // 8 bf16 = 4 VGPR
typedef __attribute__((ext_vector_type(4))) short short4v;  // 4 bf16 = 8B
typedef __attribute__((ext_vector_type(16))) float f32x16;  // MFMA 32x32 acc

static constexpr int TM = 128;   // edges per block
static constexpr float LN2 = 0.69314718055994530942f;
static constexpr float INV_LN2 = 1.44269504088896340736f;

__device__ __forceinline__ unsigned short f2bf(float f) {
  unsigned int u = __float_as_uint(f);
  u += 0x7fffu + ((u >> 16) & 1u);   // RNE
  return (unsigned short)(u >> 16);
}

// v_cvt_pk_bf16_f32 (gfx950): D[15:0]=bf16(a), D[31:16]=bf16(b), RNE
__device__ __forceinline__ unsigned int cvt_pk_bf16(float a, float b) {
  unsigned int r;
  asm("v_cvt_pk_bf16_f32 %0, %1, %2" : "=v"(r) : "v"(a), "v"(b));
  return r;
}

// HW transcendentals: v_exp_f32 computes 2^x, v_log_f32 computes log2(x)
__device__ __forceinline__ float hw_exp2(float x) {
  float r;
  asm("v_exp_f32 %0, %1" : "=v"(r) : "v"(x));
  return r;
}
__device__ __forceinline__ float hw_log2(float x) {
  float r;
  asm("v_log_f32 %0, %1" : "=v"(r) : "v"(x));
  return r;
}

// softplus(x)-ln2 via HW exp2/log2: max(x,0)-ln2 + ln2*log2(1+2^(-|x|/ln2))
// ~7 VALU instrs (2 transcendental); rel err ~1e-5, fine vs 7.5e-2 threshold.
__device__ __forceinline__ float shsp(float x) {
  float t = hw_exp2(-fabsf(x) * INV_LN2);
  float l = hw_log2(1.0f + t);
  return fmaf(LN2, l, fmaxf(x, 0.0f) - LN2);
}

// ---- prep: h (N*64 f32) -> bf16 ----
__global__ void prep_h_kernel(const float* __restrict__ h,
                              unsigned short* __restrict__ hbf, int n4) {
  int i = blockIdx.x * 256 + threadIdx.x;
  if (i < n4) {
    float4 v = reinterpret_cast<const float4*>(h)[i];
    uint2 o;
    o.x = cvt_pk_bf16(v.x, v.y);
    o.y = cvt_pk_bf16(v.z, v.w);
    reinterpret_cast<uint2*>(hbf)[i] = o;
  }
}

// ---- prep: pack W1^T, W2^T into MFMA-fragment order (bf16) ----
__global__ void prep_w_kernel(const float* __restrict__ W1,
                              const float* __restrict__ W2,
                              unsigned short* __restrict__ Wp1,
                              unsigned short* __restrict__ Wp2) {
  int j = blockIdx.x * 256 + threadIdx.x;
  if (j < 4 * 12 * 64) {
    int mt = j / (12 * 64);
    int kk = (j / 64) % 12;
    int l  = j % 64;
    int f  = mt * 32 + (l & 31);
    int kb = kk * 16 + (l >> 5) * 8;
    #pragma unroll
    for (int i = 0; i < 8; ++i)
      Wp1[(size_t)j * 8 + i] = f2bf(W1[(size_t)(kb + i) * 128 + f]);
  } else if (j < 4 * 12 * 64 + 2 * 8 * 64) {
    int jj = j - 4 * 12 * 64;
    int mt = jj / (8 * 64);
    int kk = (jj / 64) % 8;
    int l  = jj % 64;
    int oc = mt * 32 + (l & 31);
    int kb = kk * 16 + (l >> 5) * 8;
    #pragma unroll
    for (int i = 0; i < 8; ++i)
      Wp2[(size_t)jj * 8 + i] = f2bf(W2[(size_t)(kb + i) * 64 + oc]);
  }
}

// ---- main fused kernel ----
// Per block: 128 edges. One 48KB LDS tile, reused:
//   phase A (concat): 24 chunks/row of 16B  (h1 | h2 | edge_attr, bf16)
//   phase X (hidden): 16 chunks/row of 16B  (aliases chunks 0..15 — safe:
//     rows are wave-private after the barrier, and per-wave program order
//     finishes all GEMM1 reads of a row before the epilogue writes it)
__global__ __launch_bounds__(256, 3)
void edge_mlp_kernel(const float* __restrict__ ea,
                     const int* __restrict__ eidx,
                     const float* __restrict__ b1,
                     const float* __restrict__ b2,
                     const unsigned short* __restrict__ hbf,
                     const unsigned short* __restrict__ Wp1,
                     const unsigned short* __restrict__ Wp2,
                     float* __restrict__ out,
                     int E) {
  __shared__ __align__(16) unsigned char Tile[TM * 384]; // 128 rows x 24 chunks x 16B

  const int tid   = threadIdx.x;
  const int ebase = blockIdx.x * TM;

  // ---- stage h[src] (chunks 0..7), h[dst] (chunks 8..15), XOR swizzle ----
  #pragma unroll
  for (int it = 0; it < 8; ++it) {
    int ci    = it * 256 + tid;       // 0..2047 = 128 rows * 16 chunks
    int row   = ci >> 4;
    int which = (ci >> 3) & 1;
    int c     = ci & 7;
    int node  = eidx[(size_t)which * E + (ebase + row)];
    bf16x8 v = *reinterpret_cast<const bf16x8*>(hbf + (size_t)node * 64 + c * 8);
    int chunk = (which * 8 + c) ^ (row & 7);
    *reinterpret_cast<bf16x8*>(Tile + row * 384 + chunk * 16) = v;
  }
  // ---- stage edge_attr f32 -> bf16 (chunks 16..23) ----
  #pragma unroll
  for (int it = 0; it < 8; ++it) {
    int ci  = it * 256 + tid;         // 0..2047 = 128 rows * 16 quads
    int row = ci >> 4;
    int qc  = ci & 15;
    float4 v = *reinterpret_cast<const float4*>(ea + (size_t)(ebase + row) * 64 + qc * 4);
    uint2 o;
    o.x = cvt_pk_bf16(v.x, v.y);
    o.y = cvt_pk_bf16(v.z, v.w);
    int chunk = (16 + (qc >> 1)) ^ (row & 7);
    *reinterpret_cast<uint2*>(Tile + row * 384 + chunk * 16 + (qc & 1) * 8) = o;
  }
  __syncthreads();

  const int lane = tid & 63;
  const int w    = tid >> 6;
  const int lo   = lane & 31;
  const int hi   = lane >> 5;
  const int erow = w * 32 + lo;       // this wave owns rows [w*32, w*32+32)
  const int rsw  = erow & 7;

  // ---- GEMM1: x^T = W1^T(128x192) @ concat^T, 4 m-tiles of 32 feats ----
  f32x16 acc[4];
  #pragma unroll
  for (int m = 0; m < 4; ++m) acc[m] = (f32x16)0.0f;

  #pragma unroll
  for (int kk = 0; kk < 12; ++kk) {
    bf16x8 bfr = *reinterpret_cast<const bf16x8*>(
        Tile + erow * 384 + (((kk * 2 + hi) ^ rsw) * 16));
    #pragma unroll
    for (int mt = 0; mt < 4; ++mt) {
      bf16x8 afr = *reinterpret_cast<const bf16x8*>(
          Wp1 + ((size_t)(mt * 12 + kk) * 64 + lane) * 8);
      acc[mt] = __builtin_amdgcn_mfma_f32_32x32x16_bf16(afr, bfr, acc[mt], 0, 0, 0);
    }
  }

  // ---- bias + shifted softplus -> bf16 -> X rows (alias Tile, wave-private) ----
  #pragma unroll
  for (int mt = 0; mt < 4; ++mt) {
    #pragma unroll
    for (int g = 0; g < 4; ++g) {
      int f0 = mt * 32 + g * 8 + hi * 4;      // 4 consecutive features
      float4 bb = *reinterpret_cast<const float4*>(b1 + f0);
      float s0 = shsp(acc[mt][g * 4 + 0] + bb.x);
      float s1 = shsp(acc[mt][g * 4 + 1] + bb.y);
      float s2 = shsp(acc[mt][g * 4 + 2] + bb.z);
      float s3 = shsp(acc[mt][g * 4 + 3] + bb.w);
      uint2 o;
      o.x = cvt_pk_bf16(s0, s1);
      o.y = cvt_pk_bf16(s2, s3);
      int chunk = (mt * 4 + g) ^ rsw;
      *reinterpret_cast<uint2*>(Tile + erow * 384 + chunk * 16 + hi * 8) = o;
    }
  }
  // no barrier: each wave reads only its own 32 rows

  // ---- GEMM2: out^T = W2^T(64x128) @ x, 2 m-tiles of 32 ocs, K=128 ----
  f32x16 acc2[2];
  #pragma unroll
  for (int m = 0; m < 2; ++m) acc2[m] = (f32x16)0.0f;

  #pragma unroll
  for (int kk = 0; kk < 8; ++kk) {
    bf16x8 bfr = *reinterpret_cast<const bf16x8*>(
        Tile + erow * 384 + (((kk * 2 + hi) ^ rsw) * 16));
    #pragma unroll
    for (int mt = 0; mt < 2; ++mt) {
      bf16x8 afr = *reinterpret_cast<const bf16x8*>(
          Wp2 + ((size_t)(mt * 8 + kk) * 64 + lane) * 8);
      acc2[mt] = __builtin_amdgcn_mfma_f32_32x32x16_bf16(afr, bfr, acc2[mt], 0, 0, 0);
    }
  }

  // ---- bias + store: out[e][oc], 16B per store ----
  #pragma unroll
  for (int mt = 0; mt < 2; ++mt) {
    #pragma unroll
    for (int g = 0; g < 4; ++g) {
      int oc0 = mt * 32 + g * 8 + hi * 4;     // 4 consecutive out features
      float4 bb = *reinterpret_cast<const float4*>(b2 + oc0);
      float4 o;
      o.x = acc2[mt][g * 4 + 0] + bb.x;
      o.y = acc2[mt][g * 4 + 1] + bb.y;
      o.z = acc2[mt][g * 4 + 2] + bb.z;
      o.w = acc2[mt][g * 4 + 3] + bb.w;
      *reinterpret_cast<float4*>(out + (size_t)(ebase + erow) * 64 + oc0) = o;
    }
  }
}

extern "C" void kernel_launch(void* const* d_in, const int* in_sizes, int n_in,
                              void* d_out, int out_size, void* d_ws, size_t ws_size,
                              hipStream_t stream) {
  const float* h  = (const float*)d_in[0];
  const float* ea = (const float*)d_in[1];
  const int*  idx = (const int*)d_in[2];
  const float* W1 = (const float*)d_in[3];
  const float* b1 = (const float*)d_in[4];
  const float* W2 = (const float*)d_in[5];
  const float* b2 = (const float*)d_in[6];
  float* out = (float*)d_out;

  const int N = in_sizes[0] / 64;      // 50000
  const int E = in_sizes[1] / 64;      // 800000

  // workspace layout
  unsigned short* hbf = (unsigned short*)d_ws;                       // N*64 bf16
  size_t off1 = (size_t)N * 64 * 2;                                  // 16B aligned
  unsigned short* Wp1 = (unsigned short*)((char*)d_ws + off1);       // 24576 bf16
  unsigned short* Wp2 = (unsigned short*)((char*)d_ws + off1 + 24576 * 2);

  int n4 = (N * 64) / 4;
  prep_h_kernel<<<(n4 + 255) / 256, 256, 0, stream>>>(h, hbf, n4);
  prep_w_kernel<<<16, 256, 0, stream>>>(W1, W2, Wp1, Wp2);

  int nblk = E / TM;                    // 6250
  edge_mlp_kernel<<<nblk, 256, 0, stream>>>(ea, idx, b1, b2, hbf, Wp1, Wp2, out, E);
}